// Round 16
// baseline (1176.867 us; speedup 1.0000x reference)
//
#include <hip/hip_runtime.h>

// ---------------- problem constants ----------------
#define D_SZ 512
#define S_SZ 1024
#define H_SZ 2048
#define BS_SZ 32768
#define H_STEP 0.1f

typedef __attribute__((ext_vector_type(4))) float f32x4;
typedef __attribute__((ext_vector_type(8))) short s16x8;
typedef __attribute__((ext_vector_type(4))) unsigned short u16x4;
typedef unsigned short ushort_t;
typedef unsigned char u8;
typedef long long i64;

__device__ __forceinline__ ushort_t f2b(float f) {
    unsigned u = __float_as_uint(f);
    unsigned r = (u + 0x7FFFu + ((u >> 16) & 1u)) >> 16;
    return (ushort_t)r;
}
__device__ __forceinline__ float b2f(ushort_t b) {
    return __uint_as_float(((unsigned)b) << 16);
}

__device__ __forceinline__ void gload_lds16(const void* g, void* l) {
    __builtin_amdgcn_global_load_lds(
        (const __attribute__((address_space(1))) unsigned int*)g,
        (__attribute__((address_space(3))) unsigned int*)l, 16, 0, 0);
}

// ---------------- prep kernels ----------------
// W1 row-major fp8 (x8 scale): [2048h][512d]
__global__ void prep_w1r8(const float* __restrict__ W1, u8* __restrict__ W1f8r) {
    int idx4 = (blockIdx.x * 256 + threadIdx.x) * 4;   // over H*D = 1M
    f32x4 v = *(const f32x4*)(W1 + idx4);
    int r = 0;
    r = __builtin_amdgcn_cvt_pk_fp8_f32(v[0] * 8.0f, v[1] * 8.0f, r, false);
    r = __builtin_amdgcn_cvt_pk_fp8_f32(v[2] * 8.0f, v[3] * 8.0f, r, true);
    *(int*)(W1f8r + idx4) = r;
}

// transpose W1 [2048h][512d] -> W1f8 [512d][2048h], fp8 e4m3, x8 scale
__global__ void prep_w1t8(const float* __restrict__ W1, u8* __restrict__ W1f8) {
    __shared__ float t[64][65];
    int hb = blockIdx.x >> 3;      // 0..31
    int db = blockIdx.x & 7;       // 0..7
    int tr = threadIdx.x >> 2;     // 0..63
    int tc = threadIdx.x & 3;      // 0..3
    const float* src = W1 + (size_t)(hb * 64 + tr) * D_SZ + db * 64 + tc * 16;
    #pragma unroll
    for (int j = 0; j < 16; j += 4) {
        f32x4 v = *(const f32x4*)(src + j);
        t[tr][tc * 16 + j + 0] = v[0];
        t[tr][tc * 16 + j + 1] = v[1];
        t[tr][tc * 16 + j + 2] = v[2];
        t[tr][tc * 16 + j + 3] = v[3];
    }
    __syncthreads();
    u8* dst = W1f8 + (size_t)(db * 64 + tr) * H_SZ + hb * 64 + tc * 16;
    #pragma unroll
    for (int j = 0; j < 16; j += 4) {
        int r = 0;
        r = __builtin_amdgcn_cvt_pk_fp8_f32(t[tc * 16 + j + 0][tr] * 8.0f,
                                            t[tc * 16 + j + 1][tr] * 8.0f, r, false);
        r = __builtin_amdgcn_cvt_pk_fp8_f32(t[tc * 16 + j + 2][tr] * 8.0f,
                                            t[tc * 16 + j + 3][tr] * 8.0f, r, true);
        *(int*)(dst + j) = r;
    }
}

__global__ void prep_mass(const float* __restrict__ logm,
                          float* __restrict__ inv_mass,
                          float* __restrict__ mass) {
    int s = blockIdx.x * 256 + threadIdx.x;
    if (s < S_SZ) {
        float lm = logm[s];
        mass[s] = expf(lm);
        inv_mass[s] = expf(-lm);
    }
}

// ---------------- embedding + p0 (q: bf16 master qb + fp8 shadow q8) ----------------
__global__ void embed_kernel(const float* __restrict__ table,
                             const int* __restrict__ ids,
                             const float* __restrict__ mass,
                             float* __restrict__ p,
                             ushort_t* __restrict__ qb,
                             u8* __restrict__ q8) {
    int i = blockIdx.x;          // row index in [0, BS)
    int t = threadIdx.x;
    int s = i & (S_SZ - 1);
    int id = ids[i];
    int idp = (s == 0) ? id : ids[i - 1];   // s==0: prev = self -> vel 0
    float mk = (id != 0) ? 1.f : 0.f;
    float ms = mass[s];
    int d0 = t * 4;

    f32x4 cur = {0.f, 0.f, 0.f, 0.f};
    f32x4 prv = {0.f, 0.f, 0.f, 0.f};
    if (id != 0)  cur = *(const f32x4*)(table + (size_t)id  * D_SZ + d0);
    if (idp != 0) prv = *(const f32x4*)(table + (size_t)idp * D_SZ + d0);

    size_t off = (size_t)i * D_SZ + d0;
    u16x4 cb;
    cb[0] = f2b(cur[0]); cb[1] = f2b(cur[1]); cb[2] = f2b(cur[2]); cb[3] = f2b(cur[3]);
    *(u16x4*)(qb + off) = cb;
    int pk8 = 0;
    pk8 = __builtin_amdgcn_cvt_pk_fp8_f32(cur[0] * 32.f, cur[1] * 32.f, pk8, false);
    pk8 = __builtin_amdgcn_cvt_pk_fp8_f32(cur[2] * 32.f, cur[3] * 32.f, pk8, true);
    *(int*)(q8 + off) = pk8;

    f32x4 pv;
    pv[0] = ms * (cur[0] - prv[0]) * mk;
    pv[1] = ms * (cur[1] - prv[1]) * mk;
    pv[2] = ms * (cur[2] - prv[2]) * mk;
    pv[3] = ms * (cur[3] - prv[3]) * mk;
    *(f32x4*)(p + off) = pv;
}

// =====================================================================
// force1 v4 (fp8 x fp8): 256x256 tile, 1024 threads = 16 waves (4h x 4i),
// wave tile 64x64, acc[4][4]. K=512, BK=64 (8 tiles), 3 LDS bufs (96 KB),
// 2-ahead counted vmcnt(2), T2 XOR-swizzle (16B slots), setprio, XCD swz.
// A = W1f8r (x8) rows h; B = q8 (x32) rows i -> acc = 256*u.
// Epilogue: U[i,h] = fp8_e4m3(16 * sech2(u) * w2[h]).
// =====================================================================
__global__ __launch_bounds__(1024, 4) void gemm_f1(
        const u8* __restrict__ A,      // W1f8r [2048, 512]
        const u8* __restrict__ B,      // q8    [BS, 512]
        const float* __restrict__ b1,
        const float* __restrict__ W2,
        u8* __restrict__ U) {
    constexpr int KLEN = 512;
    constexpr int NT = KLEN / 64;           // 8
    __shared__ __align__(16) u8 lA[3][256 * 64];   // 48 KB
    __shared__ __align__(16) u8 lB[3][256 * 64];   // 48 KB

    const int tid = threadIdx.x;
    const int lane = tid & 63, wid = tid >> 6;
    const int wg = wid >> 2, wn = wid & 3;  // 4 (h) x 4 (i) wave grid
    const int lr = lane & 15, lk = lane >> 4;

    int wgid = ((int)blockIdx.x & 7) * 128 + ((int)blockIdx.x >> 3);  // nwg=1024
    int bxA = wgid & 7;          // 8 h-blocks
    int by  = wgid >> 3;         // 128 i-blocks
    const long a0 = (long)bxA * 256;
    const long b0 = (long)by * 256;

    const int r0  = tid >> 2;
    const int kc  = tid & 3;
    const int kcs = kc ^ ((r0 >> 1) & 3);
    const u8* gA = A + (a0 + r0) * (long)KLEN + kcs * 16;
    const u8* gB = B + (b0 + r0) * (long)KLEN + kcs * 16;

#define STAGE(t) { int _b = (t) % 3;                           \
    gload_lds16(gA + (long)(t) * 64, &lA[_b][tid * 16]);       \
    gload_lds16(gB + (long)(t) * 64, &lB[_b][tid * 16]); }

    f32x4 acc[4][4];
    #pragma unroll
    for (int m = 0; m < 4; ++m)
        #pragma unroll
        for (int n = 0; n < 4; ++n)
            acc[m][n] = (f32x4){0.f, 0.f, 0.f, 0.f};

    const int key = (lr >> 1) & 3;

    STAGE(0);
    STAGE(1);

    for (int t = 0; t < NT; ++t) {
        const int buf = t % 3;
        const u8* bA = &lA[buf][0];
        const u8* bB = &lB[buf][0];
        if (t < NT - 1) asm volatile("s_waitcnt vmcnt(2)" ::: "memory");
        else           asm volatile("s_waitcnt vmcnt(0)" ::: "memory");
        __builtin_amdgcn_s_barrier();

        #pragma unroll
        for (int x = 0; x < 2; ++x) {
            const int so = (((x * 2 + (lk >> 1)) ^ key) * 16) + (lk & 1) * 8;
            i64 a[4], b[4];
            #pragma unroll
            for (int m = 0; m < 4; ++m)
                a[m] = *(const i64*)&bA[(wg * 64 + m * 16 + lr) * 64 + so];
            #pragma unroll
            for (int n = 0; n < 4; ++n)
                b[n] = *(const i64*)&bB[(wn * 64 + n * 16 + lr) * 64 + so];
            asm volatile("s_waitcnt lgkmcnt(0)" ::: "memory");
            __builtin_amdgcn_sched_barrier(0);
            __builtin_amdgcn_s_setprio(1);
            #pragma unroll
            for (int m = 0; m < 4; ++m)
                #pragma unroll
                for (int n = 0; n < 4; ++n)
                    acc[m][n] = __builtin_amdgcn_mfma_f32_16x16x32_fp8_fp8(a[m], b[n], acc[m][n], 0, 0, 0);
            __builtin_amdgcn_s_setprio(0);
        }
        __builtin_amdgcn_s_barrier();
        if (t + 2 < NT) STAGE(t + 2);
    }
#undef STAGE

    // epilogue: u = acc/256; U[i,h] = fp8(16*sech2(u)*w2)
    #pragma unroll
    for (int m = 0; m < 4; ++m) {
        long h0 = a0 + wg * 64 + m * 16 + lk * 4;
        f32x4 b1v = *(const f32x4*)(b1 + h0);
        f32x4 w2v = *(const f32x4*)(W2 + h0);
        #pragma unroll
        for (int n = 0; n < 4; ++n) {
            long i = b0 + wn * 64 + n * 16 + lr;
            float v[4];
            #pragma unroll
            for (int j = 0; j < 4; ++j) {
                float uu = acc[m][n][j] * 0.00390625f + b1v[j];
                float e = __expf(-2.0f * fabsf(uu));
                float rc = 1.0f / (1.0f + e);
                v[j] = 64.0f * e * rc * rc * w2v[j];
            }
            int pk = 0;
            pk = __builtin_amdgcn_cvt_pk_fp8_f32(v[0], v[1], pk, false);
            pk = __builtin_amdgcn_cvt_pk_fp8_f32(v[2], v[3], pk, true);
            *(int*)(U + i * H_SZ + h0) = pk;
        }
    }
}

// =====================================================================
// force2 (fp8 x fp8): grid 512 = 2 d-halves x 256 i-tiles.
// Block = 256d x 128i, K=2048, BK=64. 8 waves = 4(d) x 2(i), 64d x 64i.
// Counted vmcnt(3).
// Epilogue: p(f32,RMW) -= (coef/128)*mask*G (direct); q-update goes
// through an LDS bounce: stash qv bf16 per-fragment -> barrier ->
// coalesced drain writes qb (64B/thr), q8 (32B/thr), qf (at wq).
// q8 produced here (q8cvt pass eliminated).
// =====================================================================
__global__ __launch_bounds__(512, 2) void gemm_f2(
        const u8* __restrict__ W1f8,   // [512][2048]
        const u8* __restrict__ Uf8,    // [BS][2048]
        const int* __restrict__ ids,
        const float* __restrict__ inv_mass,
        float* __restrict__ qf,        // f32 q output (d_out), written when wq
        float* __restrict__ p,
        ushort_t* __restrict__ qb,
        u8* __restrict__ q8,
        float coef, int do_q, int wq) {
    __shared__ __align__(16) u8 smem[49152];   // lA 2x16K | lB 2x8K ; reused as qtmp

    const int tid = threadIdx.x;
    const int lane = tid & 63, wid = tid >> 6;
    const int wd = wid >> 1, wi = wid & 1;     // 4 (d) x 2 (i)
    const int lr = lane & 15, lk = lane >> 4;

    // bijective XCD swizzle, nwg=512; d-half fastest (shares U i-tile in L2)
    int wgid = ((int)blockIdx.x & 7) * 64 + ((int)blockIdx.x >> 3);
    const int  dh = wgid & 1;
    const long a0 = (long)dh * 256;             // d base
    const long b0 = (long)(wgid >> 1) * 128;    // i base

    const int r0  = tid >> 2;                   // 0..127
    const int kc  = tid & 3;
    const int kcs = kc ^ ((r0 >> 1) & 3);
    const u8* gA = W1f8 + (a0 + r0) * (long)H_SZ + kcs * 16;
    const u8* gB = Uf8 + (b0 + r0) * (long)H_SZ + kcs * 16;

#define STG(t) { int _b = (t) & 1; \
    gload_lds16(gA + (long)(t) * 64,               smem + _b * 16384 + tid * 16); \
    gload_lds16(gA + 128L * H_SZ + (long)(t) * 64, smem + _b * 16384 + (tid + 512) * 16); \
    gload_lds16(gB + (long)(t) * 64,               smem + 32768 + _b * 8192 + tid * 16); }

    f32x4 acc[4][4];
    #pragma unroll
    for (int m = 0; m < 4; ++m)
        #pragma unroll
        for (int n = 0; n < 4; ++n)
            acc[m][n] = (f32x4){0.f, 0.f, 0.f, 0.f};

    const int key = (lr >> 1) & 3;

    STG(0);
    const int NT = H_SZ / 64;   // 32
    for (int t = 0; t < NT; ++t) {
        if (t + 1 < NT) {
            STG(t + 1);
            asm volatile("s_waitcnt vmcnt(3)" ::: "memory");
        } else {
            asm volatile("s_waitcnt vmcnt(0)" ::: "memory");
        }
        __builtin_amdgcn_s_barrier();

        const u8* bA = smem + (t & 1) * 16384;
        const u8* bB = smem + 32768 + (t & 1) * 8192;
        #pragma unroll
        for (int x = 0; x < 2; ++x) {
            const int so = (((x * 2 + (lk >> 1)) ^ key) * 16) + (lk & 1) * 8;
            i64 a[4], b[4];
            #pragma unroll
            for (int m = 0; m < 4; ++m)
                a[m] = *(const i64*)&bA[(wd * 64 + m * 16 + lr) * 64 + so];
            #pragma unroll
            for (int n = 0; n < 4; ++n)
                b[n] = *(const i64*)&bB[(wi * 64 + n * 16 + lr) * 64 + so];
            asm volatile("s_waitcnt lgkmcnt(0)" ::: "memory");
            __builtin_amdgcn_sched_barrier(0);
            __builtin_amdgcn_s_setprio(1);
            #pragma unroll
            for (int m = 0; m < 4; ++m)
                #pragma unroll
                for (int n = 0; n < 4; ++n)
                    acc[m][n] = __builtin_amdgcn_mfma_f32_16x16x32_fp8_fp8(a[m], b[n], acc[m][n], 0, 0, 0);
            __builtin_amdgcn_s_setprio(0);
        }
        __builtin_amdgcn_s_barrier();
    }
#undef STG

    // ---------------- epilogue ----------------
    // qtmp: 64 rows x 264 ushorts (padded stride) = 33792 B, reuses smem.
    ushort_t* qtmp = (ushort_t*)smem;
    const float cs = coef * (1.0f / 128.0f);

    #pragma unroll 1
    for (int ph = 0; ph < 2; ++ph) {
        if (wi == ph) {
            #pragma unroll
            for (int n = 0; n < 4; ++n) {
                long i = b0 + wi * 64 + n * 16 + lr;
                int id = ids[i];
                float cm = (id != 0) ? cs : 0.f;
                float hm = (id != 0) ? H_STEP : 0.f;
                float im = inv_mass[(int)(i & (S_SZ - 1))];
                #pragma unroll
                for (int m = 0; m < 4; ++m) {
                    long d0 = a0 + wd * 64 + m * 16 + lk * 4;
                    size_t off = (size_t)i * D_SZ + d0;
                    f32x4 pv = *(const f32x4*)(p + off);
                    #pragma unroll
                    for (int j = 0; j < 4; ++j)
                        pv[j] -= cm * acc[m][n][j];
                    *(f32x4*)(p + off) = pv;
                    if (do_q) {
                        u16x4 qo = *(const u16x4*)(qb + off);
                        u16x4 qn;
                        #pragma unroll
                        for (int j = 0; j < 4; ++j)
                            qn[j] = f2b(b2f(qo[j]) + hm * pv[j] * im);
                        int rl = n * 16 + lr;                 // 0..63
                        int dl = wd * 64 + m * 16 + lk * 4;   // 0..255
                        *(u16x4*)&qtmp[rl * 264 + dl] = qn;
                    }
                }
            }
        }
        if (do_q) {
            __syncthreads();
            // drain: 64 rows x 256 ushorts; thread -> row tid>>3, 32-ushort chunk tid&7
            int rl = tid >> 3;
            int cq = tid & 7;
            long ig = b0 + ph * 64 + rl;
            const ushort_t* src = &qtmp[rl * 264 + cq * 32];
            size_t goff = (size_t)ig * D_SZ + a0 + cq * 32;
            s16x8 w0 = *(const s16x8*)(src + 0);
            s16x8 w1 = *(const s16x8*)(src + 8);
            s16x8 w2 = *(const s16x8*)(src + 16);
            s16x8 w3 = *(const s16x8*)(src + 24);
            *(s16x8*)(qb + goff + 0)  = w0;
            *(s16x8*)(qb + goff + 8)  = w1;
            *(s16x8*)(qb + goff + 16) = w2;
            *(s16x8*)(qb + goff + 24) = w3;
            u8* q8p = q8 + goff;
            #pragma unroll
            for (int c = 0; c < 4; ++c) {
                s16x8 w = (c == 0) ? w0 : (c == 1) ? w1 : (c == 2) ? w2 : w3;
                int plo = 0, phi = 0;
                plo = __builtin_amdgcn_cvt_pk_fp8_f32(b2f((ushort_t)w[0]) * 32.f,
                                                      b2f((ushort_t)w[1]) * 32.f, plo, false);
                plo = __builtin_amdgcn_cvt_pk_fp8_f32(b2f((ushort_t)w[2]) * 32.f,
                                                      b2f((ushort_t)w[3]) * 32.f, plo, true);
                phi = __builtin_amdgcn_cvt_pk_fp8_f32(b2f((ushort_t)w[4]) * 32.f,
                                                      b2f((ushort_t)w[5]) * 32.f, phi, false);
                phi = __builtin_amdgcn_cvt_pk_fp8_f32(b2f((ushort_t)w[6]) * 32.f,
                                                      b2f((ushort_t)w[7]) * 32.f, phi, true);
                int2 r8; r8.x = plo; r8.y = phi;
                *(int2*)(q8p + c * 8) = r8;
            }
            if (wq) {
                float* qfp = qf + goff;
                #pragma unroll
                for (int c = 0; c < 4; ++c) {
                    s16x8 w = (c == 0) ? w0 : (c == 1) ? w1 : (c == 2) ? w2 : w3;
                    f32x4 lo, hi;
                    #pragma unroll
                    for (int j = 0; j < 4; ++j) {
                        lo[j] = b2f((ushort_t)w[j]);
                        hi[j] = b2f((ushort_t)w[j + 4]);
                    }
                    *(f32x4*)(qfp + c * 8 + 0) = lo;
                    *(f32x4*)(qfp + c * 8 + 4) = hi;
                }
            }
            __syncthreads();   // before ph=1 overwrites qtmp
        }
    }
}

// ---------------- host launch ----------------
extern "C" void kernel_launch(void* const* d_in, const int* in_sizes, int n_in,
                              void* d_out, int out_size, void* d_ws, size_t ws_size,
                              hipStream_t stream) {
    const float* table = (const float*)d_in[0];
    const float* logm  = (const float*)d_in[1];
    const float* W1    = (const float*)d_in[2];
    const float* b1    = (const float*)d_in[3];
    const float* W2    = (const float*)d_in[4];
    // d_in[5] = b2, unused by the force (only shifts the potential value)
    const int*   ids   = (const int*)d_in[6];

    float* qf = (float*)d_out;                      // [BS, D] f32 q (written at j=4)
    float* p  = qf + (size_t)BS_SZ * D_SZ;          // [BS, D] f32 p (master, RMW)

    char* ws = (char*)d_ws;
    size_t o = 0;
    ushort_t* qb  = (ushort_t*)(ws + o); o += (size_t)BS_SZ * D_SZ * 2;   // 32 MB (bf16 q master)
    u8* q8        = (u8*)(ws + o);       o += (size_t)BS_SZ * D_SZ;       // 16 MB (fp8 q shadow)
    u8* Uf8       = (u8*)(ws + o);       o += (size_t)BS_SZ * H_SZ;       // 64 MB
    u8* W1f8r     = (u8*)(ws + o);       o += (size_t)H_SZ * D_SZ;        // 1 MB (row-major)
    u8* W1f8      = (u8*)(ws + o);       o += (size_t)D_SZ * H_SZ;        // 1 MB (transposed)
    float* inv_mass = (float*)(ws + o);  o += S_SZ * 4;
    float* mass     = (float*)(ws + o);  o += S_SZ * 4;

    prep_w1r8<<<(H_SZ * D_SZ) / 1024, 256, 0, stream>>>(W1, W1f8r);
    prep_w1t8<<<256, 256, 0, stream>>>(W1, W1f8);
    prep_mass<<<(S_SZ + 255) / 256, 256, 0, stream>>>(logm, inv_mass, mass);
    embed_kernel<<<BS_SZ, 128, 0, stream>>>(table, ids, mass, p, qb, q8);

    // 6 distinct force evals: j=0 -> +0.05*f(q0); j=1..4 -> +0.1*f(qj); j=5 -> +0.05*f(q5)
    for (int j = 0; j < 6; ++j) {
        gemm_f1<<<1024, 1024, 0, stream>>>(W1f8r, q8, b1, W2, Uf8);
        float coef = (j == 0 || j == 5) ? 0.05f : 0.1f;
        gemm_f2<<<512, 512, 0, stream>>>(
            W1f8, Uf8, ids, inv_mass, qf, p, qb, q8, coef, (j < 5) ? 1 : 0, (j == 4) ? 1 : 0);
    }
}

// Round 17
// 1087.212 us; speedup vs baseline: 1.0825x; 1.0825x over previous
//
#include <hip/hip_runtime.h>

// ---------------- problem constants ----------------
#define D_SZ 512
#define S_SZ 1024
#define H_SZ 2048
#define BS_SZ 32768
#define H_STEP 0.1f

typedef __attribute__((ext_vector_type(4))) float f32x4;
typedef __attribute__((ext_vector_type(8))) short s16x8;
typedef __attribute__((ext_vector_type(4))) unsigned short u16x4;
typedef unsigned short ushort_t;
typedef unsigned char u8;
typedef long long i64;

__device__ __forceinline__ ushort_t f2b(float f) {
    unsigned u = __float_as_uint(f);
    unsigned r = (u + 0x7FFFu + ((u >> 16) & 1u)) >> 16;
    return (ushort_t)r;
}
__device__ __forceinline__ float b2f(ushort_t b) {
    return __uint_as_float(((unsigned)b) << 16);
}

__device__ __forceinline__ void gload_lds16(const void* g, void* l) {
    __builtin_amdgcn_global_load_lds(
        (const __attribute__((address_space(1))) unsigned int*)g,
        (__attribute__((address_space(3))) unsigned int*)l, 16, 0, 0);
}

// ---------------- prep kernels ----------------
// W1 row-major fp8 (x8 scale): [2048h][512d]
__global__ void prep_w1r8(const float* __restrict__ W1, u8* __restrict__ W1f8r) {
    int idx4 = (blockIdx.x * 256 + threadIdx.x) * 4;   // over H*D = 1M
    f32x4 v = *(const f32x4*)(W1 + idx4);
    int r = 0;
    r = __builtin_amdgcn_cvt_pk_fp8_f32(v[0] * 8.0f, v[1] * 8.0f, r, false);
    r = __builtin_amdgcn_cvt_pk_fp8_f32(v[2] * 8.0f, v[3] * 8.0f, r, true);
    *(int*)(W1f8r + idx4) = r;
}

// transpose W1 [2048h][512d] -> W1f8 [512d][2048h], fp8 e4m3, x8 scale
__global__ void prep_w1t8(const float* __restrict__ W1, u8* __restrict__ W1f8) {
    __shared__ float t[64][65];
    int hb = blockIdx.x >> 3;      // 0..31
    int db = blockIdx.x & 7;       // 0..7
    int tr = threadIdx.x >> 2;     // 0..63
    int tc = threadIdx.x & 3;      // 0..3
    const float* src = W1 + (size_t)(hb * 64 + tr) * D_SZ + db * 64 + tc * 16;
    #pragma unroll
    for (int j = 0; j < 16; j += 4) {
        f32x4 v = *(const f32x4*)(src + j);
        t[tr][tc * 16 + j + 0] = v[0];
        t[tr][tc * 16 + j + 1] = v[1];
        t[tr][tc * 16 + j + 2] = v[2];
        t[tr][tc * 16 + j + 3] = v[3];
    }
    __syncthreads();
    u8* dst = W1f8 + (size_t)(db * 64 + tr) * H_SZ + hb * 64 + tc * 16;
    #pragma unroll
    for (int j = 0; j < 16; j += 4) {
        int r = 0;
        r = __builtin_amdgcn_cvt_pk_fp8_f32(t[tc * 16 + j + 0][tr] * 8.0f,
                                            t[tc * 16 + j + 1][tr] * 8.0f, r, false);
        r = __builtin_amdgcn_cvt_pk_fp8_f32(t[tc * 16 + j + 2][tr] * 8.0f,
                                            t[tc * 16 + j + 3][tr] * 8.0f, r, true);
        *(int*)(dst + j) = r;
    }
}

__global__ void prep_mass(const float* __restrict__ logm,
                          float* __restrict__ inv_mass,
                          float* __restrict__ mass) {
    int s = blockIdx.x * 256 + threadIdx.x;
    if (s < S_SZ) {
        float lm = logm[s];
        mass[s] = expf(lm);
        inv_mass[s] = expf(-lm);
    }
}

// ---------------- coalesced qb(bf16) -> q8(fp8 x32) conversion ----------------
// 8 elems/thread: 16B read, 8B write, fully coalesced.
__global__ void q8cvt(const ushort_t* __restrict__ qb, u8* __restrict__ q8) {
    size_t idx8 = ((size_t)blockIdx.x * 256 + threadIdx.x) * 8;   // over BS*D
    s16x8 v = *(const s16x8*)(qb + idx8);
    int lo = 0, hi = 0;
    lo = __builtin_amdgcn_cvt_pk_fp8_f32(b2f((ushort_t)v[0]) * 32.f,
                                         b2f((ushort_t)v[1]) * 32.f, lo, false);
    lo = __builtin_amdgcn_cvt_pk_fp8_f32(b2f((ushort_t)v[2]) * 32.f,
                                         b2f((ushort_t)v[3]) * 32.f, lo, true);
    hi = __builtin_amdgcn_cvt_pk_fp8_f32(b2f((ushort_t)v[4]) * 32.f,
                                         b2f((ushort_t)v[5]) * 32.f, hi, false);
    hi = __builtin_amdgcn_cvt_pk_fp8_f32(b2f((ushort_t)v[6]) * 32.f,
                                         b2f((ushort_t)v[7]) * 32.f, hi, true);
    int2 r; r.x = lo; r.y = hi;
    *(int2*)(q8 + idx8) = r;
}

// ---------------- embedding + p0 (q: bf16 master qb + fp8 shadow q8) ----------------
__global__ void embed_kernel(const float* __restrict__ table,
                             const int* __restrict__ ids,
                             const float* __restrict__ mass,
                             float* __restrict__ p,
                             ushort_t* __restrict__ qb,
                             u8* __restrict__ q8) {
    int i = blockIdx.x;          // row index in [0, BS)
    int t = threadIdx.x;
    int s = i & (S_SZ - 1);
    int id = ids[i];
    int idp = (s == 0) ? id : ids[i - 1];   // s==0: prev = self -> vel 0
    float mk = (id != 0) ? 1.f : 0.f;
    float ms = mass[s];
    int d0 = t * 4;

    f32x4 cur = {0.f, 0.f, 0.f, 0.f};
    f32x4 prv = {0.f, 0.f, 0.f, 0.f};
    if (id != 0)  cur = *(const f32x4*)(table + (size_t)id  * D_SZ + d0);
    if (idp != 0) prv = *(const f32x4*)(table + (size_t)idp * D_SZ + d0);

    size_t off = (size_t)i * D_SZ + d0;
    u16x4 cb;
    cb[0] = f2b(cur[0]); cb[1] = f2b(cur[1]); cb[2] = f2b(cur[2]); cb[3] = f2b(cur[3]);
    *(u16x4*)(qb + off) = cb;
    int pk8 = 0;
    pk8 = __builtin_amdgcn_cvt_pk_fp8_f32(cur[0] * 32.f, cur[1] * 32.f, pk8, false);
    pk8 = __builtin_amdgcn_cvt_pk_fp8_f32(cur[2] * 32.f, cur[3] * 32.f, pk8, true);
    *(int*)(q8 + off) = pk8;

    f32x4 pv;
    pv[0] = ms * (cur[0] - prv[0]) * mk;
    pv[1] = ms * (cur[1] - prv[1]) * mk;
    pv[2] = ms * (cur[2] - prv[2]) * mk;
    pv[3] = ms * (cur[3] - prv[3]) * mk;
    *(f32x4*)(p + off) = pv;
}

// =====================================================================
// force1 v4 (fp8 x fp8): 256x256 tile, 1024 threads = 16 waves (4h x 4i),
// wave tile 64x64, acc[4][4]. K=512, BK=64 (8 tiles), 3 LDS bufs (96 KB),
// 2-ahead counted vmcnt(2), T2 XOR-swizzle (16B slots), setprio, XCD swz.
// A = W1f8r (x8) rows h; B = q8 (x32) rows i -> acc = 256*u.
// Epilogue: U[i,h] = fp8_e4m3(16 * sech2(u) * w2[h]).
// =====================================================================
__global__ __launch_bounds__(1024, 4) void gemm_f1(
        const u8* __restrict__ A,      // W1f8r [2048, 512]
        const u8* __restrict__ B,      // q8    [BS, 512]
        const float* __restrict__ b1,
        const float* __restrict__ W2,
        u8* __restrict__ U) {
    constexpr int KLEN = 512;
    constexpr int NT = KLEN / 64;           // 8
    __shared__ __align__(16) u8 lA[3][256 * 64];   // 48 KB
    __shared__ __align__(16) u8 lB[3][256 * 64];   // 48 KB

    const int tid = threadIdx.x;
    const int lane = tid & 63, wid = tid >> 6;
    const int wg = wid >> 2, wn = wid & 3;  // 4 (h) x 4 (i) wave grid
    const int lr = lane & 15, lk = lane >> 4;

    int wgid = ((int)blockIdx.x & 7) * 128 + ((int)blockIdx.x >> 3);  // nwg=1024
    int bxA = wgid & 7;          // 8 h-blocks
    int by  = wgid >> 3;         // 128 i-blocks
    const long a0 = (long)bxA * 256;
    const long b0 = (long)by * 256;

    const int r0  = tid >> 2;
    const int kc  = tid & 3;
    const int kcs = kc ^ ((r0 >> 1) & 3);
    const u8* gA = A + (a0 + r0) * (long)KLEN + kcs * 16;
    const u8* gB = B + (b0 + r0) * (long)KLEN + kcs * 16;

#define STAGE(t) { int _b = (t) % 3;                           \
    gload_lds16(gA + (long)(t) * 64, &lA[_b][tid * 16]);       \
    gload_lds16(gB + (long)(t) * 64, &lB[_b][tid * 16]); }

    f32x4 acc[4][4];
    #pragma unroll
    for (int m = 0; m < 4; ++m)
        #pragma unroll
        for (int n = 0; n < 4; ++n)
            acc[m][n] = (f32x4){0.f, 0.f, 0.f, 0.f};

    const int key = (lr >> 1) & 3;

    STAGE(0);
    STAGE(1);

    for (int t = 0; t < NT; ++t) {
        const int buf = t % 3;
        const u8* bA = &lA[buf][0];
        const u8* bB = &lB[buf][0];
        if (t < NT - 1) asm volatile("s_waitcnt vmcnt(2)" ::: "memory");
        else           asm volatile("s_waitcnt vmcnt(0)" ::: "memory");
        __builtin_amdgcn_s_barrier();

        #pragma unroll
        for (int x = 0; x < 2; ++x) {
            const int so = (((x * 2 + (lk >> 1)) ^ key) * 16) + (lk & 1) * 8;
            i64 a[4], b[4];
            #pragma unroll
            for (int m = 0; m < 4; ++m)
                a[m] = *(const i64*)&bA[(wg * 64 + m * 16 + lr) * 64 + so];
            #pragma unroll
            for (int n = 0; n < 4; ++n)
                b[n] = *(const i64*)&bB[(wn * 64 + n * 16 + lr) * 64 + so];
            asm volatile("s_waitcnt lgkmcnt(0)" ::: "memory");
            __builtin_amdgcn_sched_barrier(0);
            __builtin_amdgcn_s_setprio(1);
            #pragma unroll
            for (int m = 0; m < 4; ++m)
                #pragma unroll
                for (int n = 0; n < 4; ++n)
                    acc[m][n] = __builtin_amdgcn_mfma_f32_16x16x32_fp8_fp8(a[m], b[n], acc[m][n], 0, 0, 0);
            __builtin_amdgcn_s_setprio(0);
        }
        __builtin_amdgcn_s_barrier();
        if (t + 2 < NT) STAGE(t + 2);
    }
#undef STAGE

    // epilogue: u = acc/256; U[i,h] = fp8(16*sech2(u)*w2)
    #pragma unroll
    for (int m = 0; m < 4; ++m) {
        long h0 = a0 + wg * 64 + m * 16 + lk * 4;
        f32x4 b1v = *(const f32x4*)(b1 + h0);
        f32x4 w2v = *(const f32x4*)(W2 + h0);
        #pragma unroll
        for (int n = 0; n < 4; ++n) {
            long i = b0 + wn * 64 + n * 16 + lr;
            float v[4];
            #pragma unroll
            for (int j = 0; j < 4; ++j) {
                float uu = acc[m][n][j] * 0.00390625f + b1v[j];
                float e = __expf(-2.0f * fabsf(uu));
                float rc = 1.0f / (1.0f + e);
                v[j] = 64.0f * e * rc * rc * w2v[j];
            }
            int pk = 0;
            pk = __builtin_amdgcn_cvt_pk_fp8_f32(v[0], v[1], pk, false);
            pk = __builtin_amdgcn_cvt_pk_fp8_f32(v[2], v[3], pk, true);
            *(int*)(U + i * H_SZ + h0) = pk;
        }
    }
}

// =====================================================================
// force2 (fp8 x fp8): grid 512 = 2 d-halves x 256 i-tiles.
// Block = 256d x 128i, K=2048, BK=64. 8 waves = 4(d) x 2(i), 64d x 64i.
// Counted vmcnt(3). Epilogue (R12-measured form, NO q8 store):
//   p(f32,RMW) -= (coef/128)*mask*G
//   if do_q: q = b2f(qb) + 0.1*p/m*mask -> qb (bf16); if wq also q f32 out.
// =====================================================================
__global__ __launch_bounds__(512, 2) void gemm_f2(
        const u8* __restrict__ W1f8,   // [512][2048]
        const u8* __restrict__ Uf8,    // [BS][2048]
        const int* __restrict__ ids,
        const float* __restrict__ inv_mass,
        float* __restrict__ qf,        // f32 q output (d_out), written when wq
        float* __restrict__ p,
        ushort_t* __restrict__ qb,
        float coef, int do_q, int wq) {
    __shared__ __align__(16) u8 lA[2][256 * 64];   // 32 KB
    __shared__ __align__(16) u8 lB[2][128 * 64];   // 16 KB

    const int tid = threadIdx.x;
    const int lane = tid & 63, wid = tid >> 6;
    const int wd = wid >> 1, wi = wid & 1;     // 4 (d) x 2 (i)
    const int lr = lane & 15, lk = lane >> 4;

    // bijective XCD swizzle, nwg=512; d-half fastest (shares U i-tile in L2)
    int wgid = ((int)blockIdx.x & 7) * 64 + ((int)blockIdx.x >> 3);
    const int  dh = wgid & 1;
    const long a0 = (long)dh * 256;             // d base
    const long b0 = (long)(wgid >> 1) * 128;    // i base

    const int r0  = tid >> 2;                   // 0..127
    const int kc  = tid & 3;
    const int kcs = kc ^ ((r0 >> 1) & 3);
    const u8* gA = W1f8 + (a0 + r0) * (long)H_SZ + kcs * 16;
    const u8* gB = Uf8 + (b0 + r0) * (long)H_SZ + kcs * 16;

#define STG(t) { int _b = (t) & 1; \
    gload_lds16(gA + (long)(t) * 64,               &lA[_b][tid * 16]); \
    gload_lds16(gA + 128L * H_SZ + (long)(t) * 64, &lA[_b][(tid + 512) * 16]); \
    gload_lds16(gB + (long)(t) * 64,               &lB[_b][tid * 16]); }

    f32x4 acc[4][4];
    #pragma unroll
    for (int m = 0; m < 4; ++m)
        #pragma unroll
        for (int n = 0; n < 4; ++n)
            acc[m][n] = (f32x4){0.f, 0.f, 0.f, 0.f};

    const int key = (lr >> 1) & 3;

    STG(0);
    const int NT = H_SZ / 64;   // 32
    for (int t = 0; t < NT; ++t) {
        if (t + 1 < NT) {
            STG(t + 1);
            asm volatile("s_waitcnt vmcnt(3)" ::: "memory");
        } else {
            asm volatile("s_waitcnt vmcnt(0)" ::: "memory");
        }
        __builtin_amdgcn_s_barrier();

        const u8* bA = &lA[t & 1][0];
        const u8* bB = &lB[t & 1][0];
        #pragma unroll
        for (int x = 0; x < 2; ++x) {
            // 8B fragment, k32-subtile x: slot c = x*2 + (lk>>1), XOR key
            const int so = (((x * 2 + (lk >> 1)) ^ key) * 16) + (lk & 1) * 8;
            i64 a[4], b[4];
            #pragma unroll
            for (int m = 0; m < 4; ++m)
                a[m] = *(const i64*)&bA[(wd * 64 + m * 16 + lr) * 64 + so];
            #pragma unroll
            for (int n = 0; n < 4; ++n)
                b[n] = *(const i64*)&bB[(wi * 64 + n * 16 + lr) * 64 + so];
            asm volatile("s_waitcnt lgkmcnt(0)" ::: "memory");
            __builtin_amdgcn_sched_barrier(0);
            __builtin_amdgcn_s_setprio(1);
            #pragma unroll
            for (int m = 0; m < 4; ++m)
                #pragma unroll
                for (int n = 0; n < 4; ++n)
                    acc[m][n] = __builtin_amdgcn_mfma_f32_16x16x32_fp8_fp8(a[m], b[n], acc[m][n], 0, 0, 0);
            __builtin_amdgcn_s_setprio(0);
        }
        __builtin_amdgcn_s_barrier();
    }
#undef STG

    // epilogue: p -= (coef/128)*mask*G ; q = qb + 0.1*p/m*mask -> qb (+ f32 at wq)
    const float cs = coef * (1.0f / 128.0f);
    #pragma unroll
    for (int n = 0; n < 4; ++n) {
        long i = b0 + wi * 64 + n * 16 + lr;
        int id = ids[i];
        float cm = (id != 0) ? cs : 0.f;
        float hm = (id != 0) ? H_STEP : 0.f;
        float im = inv_mass[(int)(i & (S_SZ - 1))];
        #pragma unroll
        for (int m = 0; m < 4; ++m) {
            long d0 = a0 + wd * 64 + m * 16 + lk * 4;
            size_t off = (size_t)i * D_SZ + d0;
            f32x4 pv = *(const f32x4*)(p + off);
            #pragma unroll
            for (int j = 0; j < 4; ++j)
                pv[j] -= cm * acc[m][n][j];
            *(f32x4*)(p + off) = pv;
            if (do_q) {
                u16x4 qo = *(const u16x4*)(qb + off);
                f32x4 qv;
                u16x4 qn;
                #pragma unroll
                for (int j = 0; j < 4; ++j) {
                    qv[j] = b2f(qo[j]) + hm * pv[j] * im;
                    qn[j] = f2b(qv[j]);
                }
                *(u16x4*)(qb + off) = qn;
                if (wq) *(f32x4*)(qf + off) = qv;
            }
        }
    }
}

// ---------------- host launch ----------------
extern "C" void kernel_launch(void* const* d_in, const int* in_sizes, int n_in,
                              void* d_out, int out_size, void* d_ws, size_t ws_size,
                              hipStream_t stream) {
    const float* table = (const float*)d_in[0];
    const float* logm  = (const float*)d_in[1];
    const float* W1    = (const float*)d_in[2];
    const float* b1    = (const float*)d_in[3];
    const float* W2    = (const float*)d_in[4];
    // d_in[5] = b2, unused by the force (only shifts the potential value)
    const int*   ids   = (const int*)d_in[6];

    float* qf = (float*)d_out;                      // [BS, D] f32 q (written at j=4)
    float* p  = qf + (size_t)BS_SZ * D_SZ;          // [BS, D] f32 p (master, RMW)

    char* ws = (char*)d_ws;
    size_t o = 0;
    ushort_t* qb  = (ushort_t*)(ws + o); o += (size_t)BS_SZ * D_SZ * 2;   // 32 MB (bf16 q master)
    u8* q8        = (u8*)(ws + o);       o += (size_t)BS_SZ * D_SZ;       // 16 MB (fp8 q shadow)
    u8* Uf8       = (u8*)(ws + o);       o += (size_t)BS_SZ * H_SZ;       // 64 MB
    u8* W1f8r     = (u8*)(ws + o);       o += (size_t)H_SZ * D_SZ;        // 1 MB (row-major)
    u8* W1f8      = (u8*)(ws + o);       o += (size_t)D_SZ * H_SZ;        // 1 MB (transposed)
    float* inv_mass = (float*)(ws + o);  o += S_SZ * 4;
    float* mass     = (float*)(ws + o);  o += S_SZ * 4;

    prep_w1r8<<<(H_SZ * D_SZ) / 1024, 256, 0, stream>>>(W1, W1f8r);
    prep_w1t8<<<256, 256, 0, stream>>>(W1, W1f8);
    prep_mass<<<(S_SZ + 255) / 256, 256, 0, stream>>>(logm, inv_mass, mass);
    embed_kernel<<<BS_SZ, 128, 0, stream>>>(table, ids, mass, p, qb, q8);

    // 6 distinct force evals: j=0 -> +0.05*f(q0); j=1..4 -> +0.1*f(qj); j=5 -> +0.05*f(q5)
    for (int j = 0; j < 6; ++j) {
        gemm_f1<<<1024, 1024, 0, stream>>>(W1f8r, q8, b1, W2, Uf8);
        float coef = (j == 0 || j == 5) ? 0.05f : 0.1f;
        gemm_f2<<<512, 512, 0, stream>>>(
            W1f8, Uf8, ids, inv_mass, qf, p, qb, coef, (j < 5) ? 1 : 0, (j == 4) ? 1 : 0);
        if (j < 5)
            q8cvt<<<(BS_SZ * D_SZ) / (256 * 8), 256, 0, stream>>>(qb, q8);
    }
}